// Round 9
// baseline (813.688 us; speedup 1.0000x reference)
//
#include <hip/hip_runtime.h>
#include <hip/hip_bf16.h>

constexpr int B_ = 2, HQ_ = 16, HP_ = 8, S_ = 2048, D_ = 64, DV_ = 128;
constexpr float LAMB0 = 0.8f;
constexpr float EPSV = 1e-5f;

constexpr int TQ = 64, TK = 32;
constexpr int KSTR = 76;  // shorts per K row: 152 B = 38 dwords (odd/2) -> conflict-free
constexpr int VSTR = 36;  // shorts per V^T row: 72 B = 18 dwords -> conflict-free

typedef __attribute__((ext_vector_type(8))) short bf16x8;
typedef __attribute__((ext_vector_type(4))) float f32x4;
typedef __attribute__((ext_vector_type(8))) float f32x8;

__device__ __forceinline__ unsigned short f2bf(float x) {
  __hip_bfloat16 h = __float2bfloat16(x);  // RNE
  unsigned short u;
  __builtin_memcpy(&u, &h, 2);
  return u;
}
__device__ __forceinline__ float bf2f(unsigned short h) {
  return __uint_as_float((unsigned)h << 16);
}
__device__ __forceinline__ unsigned pack2(unsigned short a, unsigned short b) {
  return (unsigned)a | ((unsigned)b << 16);
}
__device__ __forceinline__ void split8v(f32x8 x, bf16x8& hi, bf16x8& lo) {
  union { bf16x8 v; unsigned short s[8]; } H, L;
#pragma unroll
  for (int j = 0; j < 8; ++j) {
    unsigned short h = f2bf(x[j]);
    H.s[j] = h;
    L.s[j] = f2bf(x[j] - bf2f(h));
  }
  hi = H.v;
  lo = L.v;
}

// ---------------------------------------------------------------------------
// Differential flash attention, bf16x3 MFMA emulation.
// R9 = R8 head-split 8-wave blocks + DOUBLE-BUFFERED K/V LDS (75.8 KB; free
// at 2 blocks/CU which the 512-block grid dictates anyway) -> ONE barrier per
// k-tile, next tile's global loads in flight during barrier+compute; plus
// odd-dword LDS strides (KSTR=76, VSTR=36) killing the 4-way bank conflicts.
// ---------------------------------------------------------------------------
__launch_bounds__(512, 4)
__global__ void diffattn_fwd(const float* __restrict__ qg, const float* __restrict__ kg,
                             const float* __restrict__ vg,
                             const float* __restrict__ lq1, const float* __restrict__ lk1,
                             const float* __restrict__ lq2, const float* __restrict__ lk2,
                             float* __restrict__ Obuf, float* __restrict__ stats) {
  // staging layout: K dbuf [2][2][2][TK][KSTR] = 38,912 B at offset 0
  //                 V dbuf [2][2][DV_][VSTR]  = 36,864 B at offset 38,912
  // merge buffer (epilogue only) aliases the base: 4*32*64 floats = 32 KB
  __shared__ __align__(16) char smem[75776];
  auto Kl = reinterpret_cast<short(*)[2][2][TK][KSTR]>(smem);
  auto Vt = reinterpret_cast<short(*)[2][DV_][VSTR]>(smem + 38912);
  float* mbuf = reinterpret_cast<float*>(smem);
  __shared__ float redbuf[8];

  const int tid = threadIdx.x;
  const int w = tid >> 6;      // 0..7
  const int hw = w >> 2;       // head of this wave
  const int qs = w & 3;        // q-strip
  const int l = tid & 63;
  const int g = l >> 4;
  const int li = l & 15;

  const int t = blockIdx.x;
  const int bh = t & 15;
  const int b = bh >> 3;
  const int hp = bh & 7;
  const int u = t >> 4;
  const int qt = (u & 1) ? (31 - (u >> 1)) : (u >> 1);  // causal load pairing
  const int q0 = qt * TQ;
  const int qw = q0 + qs * 16;

  float d1 = 0.f, d2 = 0.f;
  for (int i = 0; i < D_; ++i) { d1 += lq1[i] * lk1[i]; d2 += lq2[i] * lk2[i]; }
  const float lam = __expf(d1) - __expf(d2) + LAMB0;

  // ---- Q fragments (this wave's head only), hi/lo split ----
  bf16x8 qhi[2], qlo[2];
#pragma unroll
  for (int c = 0; c < 2; ++c) {
    const float* p = qg + (((size_t)b * HQ_ + 2 * hp + hw) * S_ + qw + li) * D_ + c * 32 + g * 8;
    f32x8 x = *reinterpret_cast<const f32x8*>(p);
    split8v(x, qhi[c], qlo[c]);
  }

  float mreg = 0.f;  // ghostmax init m=0, l=1 (implicit zero logit)
  float lreg = 1.f;
  const f32x4 zero4 = {0.f, 0.f, 0.f, 0.f};
  f32x4 Oacc[8];
#pragma unroll
  for (int d = 0; d < 8; ++d) Oacc[d] = zero4;

  // staging roles (512 threads: K 4096 floats + V 4096 floats per tile)
  const int khs = tid >> 8;        // K: head
  const int kidx = tid & 255;
  const int krow = kidx >> 3;      // 0..31
  const int kcol8 = (kidx & 7) * 8;
  const float* kb0 = kg + ((size_t)b * HQ_ + 2 * hp + khs) * S_ * D_;
  const int vdv = tid & 127;       // V: dv lane
  const int vk8 = (tid >> 7) * 8;  // 0,8,16,24
  const float* vb0 = vg + ((size_t)b * HP_ + hp) * S_ * DV_ + vdv;
  const int vswz = ((vdv >> 3) & 3) << 3;
  const int vcolw = vk8 ^ vswz;

  const int nkt = (q0 + TQ) / TK;

  // issue tile 0 loads
  f32x8 kx, vx;
  kx = *reinterpret_cast<const f32x8*>(kb0 + (size_t)krow * D_ + kcol8);
#pragma unroll
  for (int j = 0; j < 8; ++j) vx[j] = vb0[(size_t)(vk8 + j) * DV_];

  for (int kt = 0; kt < nkt; ++kt) {
    const int k0 = kt * TK;
    const int p_ = kt & 1;

    // ---- cvt + write tile kt into buf p_ (regs kx,vx from prior issue) ----
    {
      bf16x8 hi, lo;
      split8v(kx, hi, lo);
      *reinterpret_cast<bf16x8*>(&Kl[p_][khs][0][krow][kcol8]) = hi;
      *reinterpret_cast<bf16x8*>(&Kl[p_][khs][1][krow][kcol8]) = lo;
      split8v(vx, hi, lo);
      *reinterpret_cast<bf16x8*>(&Vt[p_][0][vdv][vcolw]) = hi;
      *reinterpret_cast<bf16x8*>(&Vt[p_][1][vdv][vcolw]) = lo;
    }
    // ---- issue tile kt+1 loads (fly during barrier + compute) ----
    if (kt + 1 < nkt) {
      const int kn = (kt + 1) * TK;
      kx = *reinterpret_cast<const f32x8*>(kb0 + (size_t)(kn + krow) * D_ + kcol8);
      const float* vb = vb0 + (size_t)kn * DV_;
#pragma unroll
      for (int j = 0; j < 8; ++j) vx[j] = vb[(size_t)(vk8 + j) * DV_];
    }
    __syncthreads();  // buf p_ ready; prior reads of buf p_^1 all retired

    if (k0 > qw + 15) continue;  // fully masked for this wave
    const bool needmask = (k0 + TK - 1 > qw);
    const int qglob = qw + li;

    // ---- K fragments (A-operand of S^T = K*Q^T), this head ----
    bf16x8 kf[2][2][2];  // [hl][ms][chunk]
#pragma unroll
    for (int hl = 0; hl < 2; ++hl)
#pragma unroll
      for (int ms = 0; ms < 2; ++ms)
#pragma unroll
        for (int c = 0; c < 2; ++c)
          kf[hl][ms][c] =
              *reinterpret_cast<const bf16x8*>(&Kl[p_][hw][hl][ms * 16 + li][c * 32 + g * 8]);

    f32x4 sT[2] = {zero4, zero4};
    __builtin_amdgcn_s_setprio(1);
#pragma unroll
    for (int ms = 0; ms < 2; ++ms)
#pragma unroll
      for (int c = 0; c < 2; ++c) {
        sT[ms] = __builtin_amdgcn_mfma_f32_16x16x32_bf16(kf[0][ms][c], qhi[c], sT[ms], 0, 0, 0);
        sT[ms] = __builtin_amdgcn_mfma_f32_16x16x32_bf16(kf[0][ms][c], qlo[c], sT[ms], 0, 0, 0);
        sT[ms] = __builtin_amdgcn_mfma_f32_16x16x32_bf16(kf[1][ms][c], qhi[c], sT[ms], 0, 0, 0);
      }
    __builtin_amdgcn_s_setprio(0);

    // ---- online ghostmax (lane: q=li, k=16ms+4g+r) ----
    float sv[2][4];
#pragma unroll
    for (int ms = 0; ms < 2; ++ms)
#pragma unroll
      for (int r = 0; r < 4; ++r) {
        float v = sT[ms][r] * 0.125f;
        if (needmask && (k0 + ms * 16 + g * 4 + r > qglob)) v = -1e30f;
        sv[ms][r] = v;
      }
    float tmax = fmaxf(fmaxf(fmaxf(sv[0][0], sv[0][1]), fmaxf(sv[0][2], sv[0][3])),
                       fmaxf(fmaxf(sv[1][0], sv[1][1]), fmaxf(sv[1][2], sv[1][3])));
    tmax = fmaxf(tmax, __shfl_xor(tmax, 16));
    tmax = fmaxf(tmax, __shfl_xor(tmax, 32));

    if (__any(tmax > mreg + 8.f)) {  // defer-max: rarely fires
      const float mnew = fmaxf(mreg, tmax);
      const float fh = __expf(mreg - mnew);
      mreg = mnew;
      lreg *= fh;
      float fr[4];
#pragma unroll
      for (int r = 0; r < 4; ++r) fr[r] = __shfl(fh, 20 * g + r);
#pragma unroll
      for (int d = 0; d < 8; ++d) {
        f32x4 o = Oacc[d];
        o[0] *= fr[0]; o[1] *= fr[1]; o[2] *= fr[2]; o[3] *= fr[3];
        Oacc[d] = o;
      }
    }

    float p[2][4], psum = 0.f;
#pragma unroll
    for (int ms = 0; ms < 2; ++ms)
#pragma unroll
      for (int r = 0; r < 4; ++r) {
        p[ms][r] = __expf(sv[ms][r] - mreg);
        psum += p[ms][r];
      }
    psum += __shfl_xor(psum, 16);
    psum += __shfl_xor(psum, 32);
    lreg += psum;

    // ---- P -> bf16 hi/lo, shfl lane-exchange into PV A-fragment layout ----
    unsigned ph0a = pack2(f2bf(p[0][0]), f2bf(p[0][1]));
    unsigned ph0b = pack2(f2bf(p[0][2]), f2bf(p[0][3]));
    unsigned ph1a = pack2(f2bf(p[1][0]), f2bf(p[1][1]));
    unsigned ph1b = pack2(f2bf(p[1][2]), f2bf(p[1][3]));
    float pl[2][4];
#pragma unroll
    for (int ms = 0; ms < 2; ++ms)
#pragma unroll
      for (int r = 0; r < 4; ++r) pl[ms][r] = p[ms][r] - bf2f(f2bf(p[ms][r]));
    unsigned pl0a = pack2(f2bf(pl[0][0]), f2bf(pl[0][1]));
    unsigned pl0b = pack2(f2bf(pl[0][2]), f2bf(pl[0][3]));
    unsigned pl1a = pack2(f2bf(pl[1][0]), f2bf(pl[1][1]));
    unsigned pl1b = pack2(f2bf(pl[1][2]), f2bf(pl[1][3]));

    const int srcA = 32 * (g & 1) + li;
    const int srcB = srcA + 16;
    const bool hiMs = (g >> 1) != 0;
    bf16x8 AH, AL;
    {
      union { bf16x8 v; unsigned us[4]; } U;
      unsigned a0 = (unsigned)__shfl((int)ph0a, srcA), b0 = (unsigned)__shfl((int)ph1a, srcA);
      unsigned a1 = (unsigned)__shfl((int)ph0b, srcA), b1 = (unsigned)__shfl((int)ph1b, srcA);
      unsigned a2 = (unsigned)__shfl((int)ph0a, srcB), b2 = (unsigned)__shfl((int)ph1a, srcB);
      unsigned a3 = (unsigned)__shfl((int)ph0b, srcB), b3 = (unsigned)__shfl((int)ph1b, srcB);
      U.us[0] = hiMs ? b0 : a0; U.us[1] = hiMs ? b1 : a1;
      U.us[2] = hiMs ? b2 : a2; U.us[3] = hiMs ? b3 : a3;
      AH = U.v;
    }
    {
      union { bf16x8 v; unsigned us[4]; } U;
      unsigned a0 = (unsigned)__shfl((int)pl0a, srcA), b0 = (unsigned)__shfl((int)pl1a, srcA);
      unsigned a1 = (unsigned)__shfl((int)pl0b, srcA), b1 = (unsigned)__shfl((int)pl1b, srcA);
      unsigned a2 = (unsigned)__shfl((int)pl0a, srcB), b2 = (unsigned)__shfl((int)pl1a, srcB);
      unsigned a3 = (unsigned)__shfl((int)pl0b, srcB), b3 = (unsigned)__shfl((int)pl1b, srcB);
      U.us[0] = hiMs ? b0 : a0; U.us[1] = hiMs ? b1 : a1;
      U.us[2] = hiMs ? b2 : a2; U.us[3] = hiMs ? b3 : a3;
      AL = U.v;
    }

    // ---- PV: O += P*V  (Ph*Vh + Pl*Vh + Ph*Vl) ----
    __builtin_amdgcn_s_setprio(1);
#pragma unroll
    for (int dvt = 0; dvt < 8; ++dvt) {
      const int dvr = dvt * 16 + li;
      const int vcol = (g * 8) ^ (((dvr >> 3) & 3) << 3);
      bf16x8 vh = *reinterpret_cast<const bf16x8*>(&Vt[p_][0][dvr][vcol]);
      bf16x8 vl = *reinterpret_cast<const bf16x8*>(&Vt[p_][1][dvr][vcol]);
      f32x4 acc = Oacc[dvt];
      acc = __builtin_amdgcn_mfma_f32_16x16x32_bf16(AH, vh, acc, 0, 0, 0);
      acc = __builtin_amdgcn_mfma_f32_16x16x32_bf16(AL, vh, acc, 0, 0, 0);
      acc = __builtin_amdgcn_mfma_f32_16x16x32_bf16(AH, vl, acc, 0, 0, 0);
      Oacc[dvt] = acc;
    }
    __builtin_amdgcn_s_setprio(0);
  }

  // ---- epilogue: head 1 publishes lam*O1/l1 via LDS; head 0 combines ----
  __syncthreads();  // staging LDS free -> reuse as merge buffer
  if (w >= 4) {
    float rl[4];
#pragma unroll
    for (int r = 0; r < 4; ++r) rl[r] = lam / __shfl(lreg, 20 * g + r);
#pragma unroll
    for (int dvt = 0; dvt < 8; ++dvt)
#pragma unroll
      for (int r = 0; r < 4; ++r)
        mbuf[((qs * 32 + dvt * 4 + r) * 64) + l] = Oacc[dvt][r] * rl[r];
  }
  __syncthreads();

  float lsum = 0.f, lss = 0.f;
  if (w < 4) {
    float rl[4];
#pragma unroll
    for (int r = 0; r < 4; ++r) rl[r] = 1.f / __shfl(lreg, 20 * g + r);
    float* ob = Obuf + ((size_t)(b * HP_ + hp)) * S_ * DV_;
#pragma unroll
    for (int dvt = 0; dvt < 8; ++dvt)
#pragma unroll
      for (int r = 0; r < 4; ++r) {
        float vres = Oacc[dvt][r] * rl[r] - mbuf[((qs * 32 + dvt * 4 + r) * 64) + l];
        ob[(size_t)(qw + g * 4 + r) * DV_ + dvt * 16 + li] = vres;
        lsum += vres;
        lss += vres * vres;
      }
#pragma unroll
    for (int o = 1; o < 64; o <<= 1) {
      lsum += __shfl_xor(lsum, o);
      lss += __shfl_xor(lss, o);
    }
    if (l == 0) {
      redbuf[w * 2] = lsum;
      redbuf[w * 2 + 1] = lss;
    }
  }
  __syncthreads();
  if (tid == 0) {
    const int region = ((b * HP_ + hp) << 1) | (q0 >= 1024 ? 1 : 0);
    atomicAdd(&stats[2 * region + 0], redbuf[0] + redbuf[2] + redbuf[4] + redbuf[6]);
    atomicAdd(&stats[2 * region + 1], redbuf[1] + redbuf[3] + redbuf[5] + redbuf[7]);
  }
}

// ---------------------------------------------------------------------------
// GroupNorm apply (stats from attn epilogue; 32 contiguous 131072-f regions).
// ---------------------------------------------------------------------------
__global__ void gn_apply(const float* __restrict__ O, const float* __restrict__ stats,
                         const float* __restrict__ gw, const float* __restrict__ gb,
                         float* __restrict__ out) {
  const size_t f = ((size_t)blockIdx.x * 256 + threadIdx.x) * 4;
  const int g = (int)(f >> 17);
  const int sidx = (int)((f >> 7) & 2047);
  const int hp = (int)((f >> 18) & 7);
  const int c = hp * 128 + (sidx >> 4);
  const float mean = stats[2 * g + 0] * (1.f / 131072.f);
  const float var = stats[2 * g + 1] * (1.f / 131072.f) - mean * mean;
  const float sc = rsqrtf(var + EPSV) * gw[c] * 0.2f;  // fold (1 - lambda_init)
  const float bi = gb[c] * 0.2f;
  float4 x = *reinterpret_cast<const float4*>(O + f);
  float4 y;
  y.x = (x.x - mean) * sc + bi;
  y.y = (x.y - mean) * sc + bi;
  y.z = (x.z - mean) * sc + bi;
  y.w = (x.w - mean) * sc + bi;
  *reinterpret_cast<float4*>(out + f) = y;
}

extern "C" void kernel_launch(void* const* d_in, const int* in_sizes, int n_in,
                              void* d_out, int out_size, void* d_ws, size_t ws_size,
                              hipStream_t stream) {
  const float* q = (const float*)d_in[0];
  const float* k = (const float*)d_in[1];
  const float* v = (const float*)d_in[2];
  const float* lq1 = (const float*)d_in[3];
  const float* lk1 = (const float*)d_in[4];
  const float* lq2 = (const float*)d_in[5];
  const float* lk2 = (const float*)d_in[6];
  const float* gw = (const float*)d_in[7];
  const float* gb = (const float*)d_in[8];
  float* out = (float*)d_out;

  float* Obuf = (float*)d_ws;  // [B][HP][S][DV] fp32 = 16 MiB
  float* stats = (float*)((char*)d_ws + (size_t)B_ * HP_ * S_ * DV_ * sizeof(float));

  hipMemsetAsync(stats, 0, 64 * sizeof(float), stream);
  diffattn_fwd<<<dim3(512), dim3(512), 0, stream>>>(q, k, v, lq1, lk1, lq2, lk2, Obuf, stats);
  gn_apply<<<dim3(4096), dim3(256), 0, stream>>>(Obuf, stats, gw, gb, out);
}